// Round 1
// baseline (1886.366 us; speedup 1.0000x reference)
//
#include <hip/hip_runtime.h>
#include <hip/hip_bf16.h>

// Problem constants: B=4, S=2048, D=1024, H=16, HD=64
#define BB 4
#define SS 2048
#define DD 1024
#define HH 16
#define HD 64
#define MM (BB * SS)      // 8192
#define N_QKV (3 * DD)    // 3072

// ---------------------------------------------------------------------------
// GEMM: C[M,N] = A[M,K] @ B[K,N] + bias[N]
// 128x128 tile, 256 threads, 8x8 per thread, BK=16
// ---------------------------------------------------------------------------
#define BM 128
#define BN 128
#define BK 16
#define LPAD 4

__global__ __launch_bounds__(256) void gemm_bias(
    const float* __restrict__ A, const float* __restrict__ Bm,
    const float* __restrict__ bias, float* __restrict__ C,
    int M, int N, int K) {
  __shared__ float As[BK][BM + LPAD];
  __shared__ float Bs[BK][BN + LPAD];

  const int t = threadIdx.x;
  const int tx = t & 15;        // 0..15 -> N direction
  const int ty = t >> 4;        // 0..15 -> M direction
  const int bm = blockIdx.y * BM;
  const int bn = blockIdx.x * BN;

  float acc[8][8];
#pragma unroll
  for (int i = 0; i < 8; ++i)
#pragma unroll
    for (int j = 0; j < 8; ++j) acc[i][j] = 0.f;

  for (int k0 = 0; k0 < K; k0 += BK) {
    // A tile: rows bm..bm+127, cols k0..k0+15  -> As[k][m] (transposed)
#pragma unroll
    for (int r = 0; r < 2; ++r) {
      int idx = r * 256 + t;          // 0..511
      int m = idx >> 2;               // 0..127
      int kg = (idx & 3) * 4;         // 0,4,8,12
      float4 a = *(const float4*)(&A[(size_t)(bm + m) * K + k0 + kg]);
      As[kg + 0][m] = a.x;
      As[kg + 1][m] = a.y;
      As[kg + 2][m] = a.z;
      As[kg + 3][m] = a.w;
    }
    // B tile: rows k0..k0+15, cols bn..bn+127 -> Bs[k][n]
#pragma unroll
    for (int r = 0; r < 2; ++r) {
      int idx = r * 256 + t;          // 0..511
      int kk = idx >> 5;              // 0..15
      int ng = (idx & 31) * 4;        // 0..124
      *(float4*)(&Bs[kk][ng]) =
          *(const float4*)(&Bm[(size_t)(k0 + kk) * N + bn + ng]);
    }
    __syncthreads();

#pragma unroll
    for (int kk = 0; kk < BK; ++kk) {
      float a[8], b[8];
      *(float4*)(&a[0]) = *(const float4*)(&As[kk][ty * 8]);
      *(float4*)(&a[4]) = *(const float4*)(&As[kk][ty * 8 + 4]);
      *(float4*)(&b[0]) = *(const float4*)(&Bs[kk][tx * 8]);
      *(float4*)(&b[4]) = *(const float4*)(&Bs[kk][tx * 8 + 4]);
#pragma unroll
      for (int i = 0; i < 8; ++i)
#pragma unroll
        for (int j = 0; j < 8; ++j) acc[i][j] += a[i] * b[j];
    }
    __syncthreads();
  }

  // epilogue: add bias, store
#pragma unroll
  for (int i = 0; i < 8; ++i) {
    int m = bm + ty * 8 + i;
#pragma unroll
    for (int j = 0; j < 8; j += 4) {
      int n = bn + tx * 8 + j;
      float4 o;
      o.x = acc[i][j + 0] + bias[n + 0];
      o.y = acc[i][j + 1] + bias[n + 1];
      o.z = acc[i][j + 2] + bias[n + 2];
      o.w = acc[i][j + 3] + bias[n + 3];
      *(float4*)(&C[(size_t)m * N + n]) = o;
    }
  }
}

// ---------------------------------------------------------------------------
// Flash-style causal attention, fp32.
// grid: (S/64, B*H). block: 256 threads. Each WG: 64 query rows of one head.
// qkv layout: [B, S, 3D]; q at col h*64, k at D + h*64, v at 2D + h*64.
// ctx layout: [B, S, D] merged heads.
// ---------------------------------------------------------------------------
#define QB 64
#define KB 64

__global__ __launch_bounds__(256) void flash_attn(
    const float* __restrict__ qkv, float* __restrict__ ctx) {
  __shared__ float Qt[HD][QB + LPAD];   // Q transposed: [hd][q]
  __shared__ float Kt[HD][KB + LPAD];   // K transposed: [hd][k]
  __shared__ float Vs[KB][HD + LPAD];   // V natural:    [k][hd]
  __shared__ float Ps[QB][KB + LPAD];   // P tile:       [q][k]

  const int t = threadIdx.x;
  const int tx = t & 15;   // 0..15: k-cols (S tile) / hd-cols (O tile)
  const int ty = t >> 4;   // 0..15: q-rows
  const int qblk = blockIdx.x;
  const int bh = blockIdx.y;
  const int b = bh >> 4;
  const int h = bh & 15;
  const int q0 = qblk * QB;

  const size_t rowstride = (size_t)N_QKV;
  const float* qbase = qkv + (size_t)b * SS * rowstride + h * HD;
  const float* kbase = qbase + DD;
  const float* vbase = qbase + 2 * DD;

  // load Q tile transposed: 64 rows x 64 hd
#pragma unroll
  for (int r = 0; r < 4; ++r) {
    int idx = r * 256 + t;        // 0..1023
    int row = idx >> 4;           // 0..63
    int cg = (idx & 15) * 4;      // hd group
    float4 a = *(const float4*)(&qbase[(size_t)(q0 + row) * rowstride + cg]);
    Qt[cg + 0][row] = a.x;
    Qt[cg + 1][row] = a.y;
    Qt[cg + 2][row] = a.z;
    Qt[cg + 3][row] = a.w;
  }

  float m_run[4], l_run[4], acc[4][4];
#pragma unroll
  for (int i = 0; i < 4; ++i) {
    m_run[i] = -1e30f;
    l_run[i] = 0.f;
#pragma unroll
    for (int j = 0; j < 4; ++j) acc[i][j] = 0.f;
  }

  const int nkb = qblk + 1;  // causal: only k-blocks 0..qblk
  for (int kb = 0; kb < nkb; ++kb) {
    const int k0 = kb * KB;
    __syncthreads();  // prev iter done reading Kt/Vs/Ps (and Q load visible)

    // load K transposed + V natural
#pragma unroll
    for (int r = 0; r < 4; ++r) {
      int idx = r * 256 + t;
      int row = idx >> 4;
      int cg = (idx & 15) * 4;
      float4 a = *(const float4*)(&kbase[(size_t)(k0 + row) * rowstride + cg]);
      Kt[cg + 0][row] = a.x;
      Kt[cg + 1][row] = a.y;
      Kt[cg + 2][row] = a.z;
      Kt[cg + 3][row] = a.w;
      float4 vv = *(const float4*)(&vbase[(size_t)(k0 + row) * rowstride + cg]);
      *(float4*)(&Vs[row][cg]) = vv;
    }
    __syncthreads();

    // S tile = Q @ K^T  (4x4 per thread)
    float s[4][4];
#pragma unroll
    for (int i = 0; i < 4; ++i)
#pragma unroll
      for (int j = 0; j < 4; ++j) s[i][j] = 0.f;

#pragma unroll 8
    for (int kk = 0; kk < HD; ++kk) {
      float a[4], bb[4];
      *(float4*)a = *(const float4*)(&Qt[kk][ty * 4]);
      *(float4*)bb = *(const float4*)(&Kt[kk][tx * 4]);
#pragma unroll
      for (int i = 0; i < 4; ++i)
#pragma unroll
        for (int j = 0; j < 4; ++j) s[i][j] += a[i] * bb[j];
    }

    // mask (before-scale semantics: masked = -1e5, then /8) + scale
#pragma unroll
    for (int i = 0; i < 4; ++i) {
      int qi = q0 + ty * 4 + i;
#pragma unroll
      for (int j = 0; j < 4; ++j) {
        int kj = k0 + tx * 4 + j;
        s[i][j] = (kj <= qi) ? s[i][j] * 0.125f : -12500.0f;
      }
    }

    // online softmax per row (reduce across 16 tx lanes)
#pragma unroll
    for (int i = 0; i < 4; ++i) {
      float mx = fmaxf(fmaxf(s[i][0], s[i][1]), fmaxf(s[i][2], s[i][3]));
#pragma unroll
      for (int off = 1; off < 16; off <<= 1)
        mx = fmaxf(mx, __shfl_xor(mx, off));
      float mnew = fmaxf(m_run[i], mx);
      float scale = __expf(m_run[i] - mnew);
      float lsum = 0.f;
#pragma unroll
      for (int j = 0; j < 4; ++j) {
        s[i][j] = __expf(s[i][j] - mnew);
        lsum += s[i][j];
      }
#pragma unroll
      for (int off = 1; off < 16; off <<= 1)
        lsum += __shfl_xor(lsum, off);
      l_run[i] = l_run[i] * scale + lsum;
      m_run[i] = mnew;
#pragma unroll
      for (int j = 0; j < 4; ++j) acc[i][j] *= scale;
      *(float4*)(&Ps[ty * 4 + i][tx * 4]) = *(float4*)(&s[i][0]);
    }
    __syncthreads();  // Ps visible

    // O += P @ V   (thread: rows ty*4.., hd cols tx*4..)
#pragma unroll 4
    for (int k = 0; k < KB; ++k) {
      float bb[4];
      *(float4*)bb = *(const float4*)(&Vs[k][tx * 4]);
#pragma unroll
      for (int i = 0; i < 4; ++i) {
        float p = Ps[ty * 4 + i][k];
#pragma unroll
        for (int j = 0; j < 4; ++j) acc[i][j] += p * bb[j];
      }
    }
  }

  // epilogue: normalize and write ctx [B,S,D] with merged heads
  float* cbase = ctx + (size_t)b * SS * DD + h * HD;
#pragma unroll
  for (int i = 0; i < 4; ++i) {
    float inv = 1.0f / l_run[i];
    float4 o;
    o.x = acc[i][0] * inv;
    o.y = acc[i][1] * inv;
    o.z = acc[i][2] * inv;
    o.w = acc[i][3] * inv;
    *(float4*)(&cbase[(size_t)(q0 + ty * 4 + i) * DD + tx * 4]) = o;
  }
}

// ---------------------------------------------------------------------------
extern "C" void kernel_launch(void* const* d_in, const int* in_sizes, int n_in,
                              void* d_out, int out_size, void* d_ws,
                              size_t ws_size, hipStream_t stream) {
  const float* x      = (const float*)d_in[0];  // [B,S,D]
  const float* w_attn = (const float*)d_in[1];  // [D,3D]
  const float* b_attn = (const float*)d_in[2];  // [3D]
  const float* w_proj = (const float*)d_in[3];  // [D,D]
  const float* b_proj = (const float*)d_in[4];  // [D]
  float* out = (float*)d_out;                   // [B,S,D]

  float* qkv = (float*)d_ws;                       // [M, 3D] = 100.7 MB
  float* ctx = qkv + (size_t)MM * N_QKV;           // [M, D]  =  33.6 MB

  dim3 blk(256);

  // 1) QKV = X @ W_attn + b_attn
  gemm_bias<<<dim3(N_QKV / BN, MM / BM), blk, 0, stream>>>(
      x, w_attn, b_attn, qkv, MM, N_QKV, DD);

  // 2) causal flash attention per (b,h), merged-head ctx
  flash_attn<<<dim3(SS / QB, BB * HH), blk, 0, stream>>>(qkv, ctx);

  // 3) out = ctx @ W_proj + b_proj
  gemm_bias<<<dim3(DD / BN, MM / BM), blk, 0, stream>>>(
      ctx, w_proj, b_proj, out, MM, DD, DD);
}

// Round 2
// 347.123 us; speedup vs baseline: 5.4343x; 5.4343x over previous
//
#include <hip/hip_runtime.h>
#include <hip/hip_bf16.h>

// Problem constants: B=4, S=2048, D=1024, H=16, HD=64
#define BB 4
#define SS 2048
#define DD 1024
#define HH 16
#define HD 64
#define MM (BB * SS)     // 8192
#define NQKV (3 * DD)    // 3072

typedef __attribute__((ext_vector_type(8))) _Float16 half8;
typedef __attribute__((ext_vector_type(4))) float f32x4;

static __device__ __forceinline__ unsigned short f2h(float f) {
  _Float16 h = (_Float16)f;
  return __builtin_bit_cast(unsigned short, h);
}

// async global->LDS, 16B per lane; LDS dest is wave-uniform base (+lane*16 by HW)
static __device__ __forceinline__ void gload_lds16(const void* g, void* l) {
  __builtin_amdgcn_global_load_lds(
      (const __attribute__((address_space(1))) unsigned int*)g,
      (__attribute__((address_space(3))) unsigned int*)l, 16, 0, 0);
}

// ---------------------------------------------------------------------------
// fp32 -> fp16 convert (flat, vectorized)
// ---------------------------------------------------------------------------
__global__ __launch_bounds__(256) void cvt_f16(const float* __restrict__ in,
                                               unsigned short* __restrict__ out,
                                               int n4) {
  int i = blockIdx.x * 256 + threadIdx.x;
  if (i < n4) {
    float4 v = ((const float4*)in)[i];
    ushort4 o;
    o.x = f2h(v.x); o.y = f2h(v.y); o.z = f2h(v.z); o.w = f2h(v.w);
    ((ushort4*)out)[i] = o;
  }
}

// ---------------------------------------------------------------------------
// transpose+convert: in [K][N] f32 -> out [N][K] f16, 64x64 tiles
// ---------------------------------------------------------------------------
__global__ __launch_bounds__(256) void transpose_f16(
    const float* __restrict__ in, unsigned short* __restrict__ out, int K, int N) {
  __shared__ float tile[64][65];
  const int k0 = blockIdx.y * 64, n0 = blockIdx.x * 64;
  const int t = threadIdx.x;
#pragma unroll
  for (int i = 0; i < 16; ++i) {
    int idx = i * 256 + t;
    int r = idx >> 6, c = idx & 63;
    tile[r][c] = in[(size_t)(k0 + r) * N + n0 + c];
  }
  __syncthreads();
#pragma unroll
  for (int i = 0; i < 16; ++i) {
    int idx = i * 256 + t;
    int r = idx >> 6, c = idx & 63;
    out[(size_t)(n0 + r) * K + k0 + c] = f2h(tile[c][r]);
  }
}

// ---------------------------------------------------------------------------
// fp16 MFMA GEMM: C[M,N] = A[M,K]f16 @ BT[N,K]f16^T + bias
// 128x128 tile, BK=32, 4 waves (2x2), each wave 64x64 via 4x4 16x16x32 MFMAs.
// MODE 0: out f16 -> qkv buffer (cols<2048) + transposed V buffer (cols>=2048)
// MODE 1: out f32 -> Cf
// LDS tiles [128 rows][32 cols f16] with 16B-slot swizzle: slot ^= (row>>1)&3
// ---------------------------------------------------------------------------
template <int MODE>
__global__ __launch_bounds__(256) void gemm_f16(
    const unsigned short* __restrict__ A, const unsigned short* __restrict__ BT,
    const float* __restrict__ bias, unsigned short* __restrict__ Cq,
    unsigned short* __restrict__ vT, float* __restrict__ Cf, int M, int N, int K) {
  __shared__ __align__(16) unsigned short As[128 * 32];
  __shared__ __align__(16) unsigned short Bs[128 * 32];

  const int t = threadIdx.x;
  const int lane = t & 63;
  const int w = t >> 6;
  const int wr = w >> 1, wc = w & 1;
  const int bm = blockIdx.y * 128, bn = blockIdx.x * 128;

  f32x4 acc[4][4] = {};

  // staging geometry: chunk = w*2+i (1KB each), row = chunk*16 + lane/4,
  // slot = lane&3, source slot pre-swizzled
  const int srow = (lane >> 2);
  const int sslot = (lane & 3);

  for (int k0 = 0; k0 < K; k0 += 32) {
    __syncthreads();
#pragma unroll
    for (int i = 0; i < 2; ++i) {
      int chunk = w * 2 + i;
      int row = chunk * 16 + srow;
      int cs = sslot ^ ((row >> 1) & 3);
      gload_lds16(A + (size_t)(bm + row) * K + k0 + cs * 8,
                  (char*)As + chunk * 1024);
      gload_lds16(BT + (size_t)(bn + row) * K + k0 + cs * 8,
                  (char*)Bs + chunk * 1024);
    }
    __syncthreads();

    half8 af[4], bf[4];
#pragma unroll
    for (int mb = 0; mb < 4; ++mb) {
      int row = wr * 64 + mb * 16 + (lane & 15);
      int cs = (lane >> 4) ^ ((row >> 1) & 3);
      af[mb] = *(const half8*)((const char*)As + row * 64 + cs * 16);
    }
#pragma unroll
    for (int nb = 0; nb < 4; ++nb) {
      int row = wc * 64 + nb * 16 + (lane & 15);
      int cs = (lane >> 4) ^ ((row >> 1) & 3);
      bf[nb] = *(const half8*)((const char*)Bs + row * 64 + cs * 16);
    }
#pragma unroll
    for (int mb = 0; mb < 4; ++mb)
#pragma unroll
      for (int nb = 0; nb < 4; ++nb)
        acc[mb][nb] = __builtin_amdgcn_mfma_f32_16x16x32_f16(
            af[mb], bf[nb], acc[mb][nb], 0, 0, 0);
  }

  // epilogue. C/D frag: col = lane&15, row = (lane>>4)*4 + reg
  const int g = lane >> 4;
#pragma unroll
  for (int mb = 0; mb < 4; ++mb) {
#pragma unroll
    for (int nb = 0; nb < 4; ++nb) {
      int m0 = bm + wr * 64 + mb * 16 + g * 4;
      int n = bn + wc * 64 + nb * 16 + (lane & 15);
      float bv = bias[n];
      if (MODE == 0) {
        if (n < 2 * DD) {
#pragma unroll
          for (int r = 0; r < 4; ++r)
            Cq[(size_t)(m0 + r) * NQKV + n] = f2h(acc[mb][nb][r] + bv);
        } else {
          // V: write transposed into vT[b][h][hd][s], pack 4 consecutive s
          int h = (n - 2 * DD) >> 6;
          int hd = n & 63;
          int b = m0 >> 11, s0 = m0 & 2047;
          ushort4 pk;
          unsigned short* pp = (unsigned short*)&pk;
#pragma unroll
          for (int r = 0; r < 4; ++r) pp[r] = f2h(acc[mb][nb][r] + bv);
          *(ushort4*)&vT[((size_t)((b * HH + h) * HD + hd)) * SS + s0] = pk;
        }
      } else {
#pragma unroll
        for (int r = 0; r < 4; ++r)
          Cf[(size_t)(m0 + r) * N + n] = acc[mb][nb][r] + bv;
      }
    }
  }
}

// ---------------------------------------------------------------------------
// fp16 MFMA causal flash attention.
// grid (S/64, B*H), 256 threads = 4 waves; wave w owns q-rows q0+w*16..+15.
// S^T = K·Q^T (softmax lane-local), O^T = V^T·P^T.
// K tile LDS [64 key][64 hd], V tile LDS [64 hd][64 key] (from pre-transposed
// vT global), both with 16B-slot swizzle slot ^= row&7, staged by
// global_load_lds with pre-swizzled global source columns.
// ---------------------------------------------------------------------------
__global__ __launch_bounds__(256) void flash16(
    const unsigned short* __restrict__ qkv,  // [M][3072] f16 (Q,K cols valid)
    const unsigned short* __restrict__ vT,   // [B*H*HD][S] f16
    unsigned short* __restrict__ ctx) {      // [M][1024] f16
  __shared__ __align__(16) unsigned short Kt[64 * 64];
  __shared__ __align__(16) unsigned short Vt[64 * 64];
  __shared__ __align__(16) unsigned short Ps[4][16 * 72];  // rows padded: 144B

  const int t = threadIdx.x, lane = t & 63, w = t >> 6;
  const int qblk = blockIdx.x, bh = blockIdx.y;
  const int b = bh >> 4, h = bh & 15;
  const int q0 = qblk * 64;
  const int q = lane & 15;             // this lane's q-row (within wave tile)
  const int g = lane >> 4;             // 4-lane group
  const int qrow = q0 + w * 16 + q;    // within S

  // Q fragments (direct from global): Q[qrow][hd=8g+i (+32ks)]
  half8 qf[2];
  {
    const unsigned short* qp = qkv + (size_t)(b * SS + qrow) * NQKV + h * HD;
    qf[0] = *(const half8*)(qp + g * 8);
    qf[1] = *(const half8*)(qp + 32 + g * 8);
  }

  f32x4 oacc[4] = {};
  float m_run = -1e30f, l_run = 0.f;

  const unsigned short* kg = qkv + (size_t)b * SS * NQKV + DD + h * HD;
  const unsigned short* vg = vT + (size_t)(b * HH + h) * HD * SS;
  unsigned short* pw = &Ps[w][0];

  for (int kt = 0; kt <= qblk; ++kt) {
    const int k0 = kt * 64;
    __syncthreads();  // prior PV reads of Kt/Vt done
#pragma unroll
    for (int i = 0; i < 2; ++i) {
      int chunk = w * 2 + i;
      int row = chunk * 8 + (lane >> 3);   // 128B rows
      int cs = (lane & 7) ^ (row & 7);
      gload_lds16(kg + (size_t)(k0 + row) * NQKV + cs * 8,
                  (char*)Kt + chunk * 1024);
      gload_lds16(vg + (size_t)row * SS + k0 + cs * 8,
                  (char*)Vt + chunk * 1024);
    }
    __syncthreads();

    // S^T[key][q] = K · Q^T
    f32x4 sacc[4] = {};
#pragma unroll
    for (int ks = 0; ks < 2; ++ks) {
#pragma unroll
      for (int kb = 0; kb < 4; ++kb) {
        int row = kb * 16 + q;
        int cs = (g + 4 * ks) ^ (row & 7);
        half8 kf = *(const half8*)((const char*)Kt + row * 128 + cs * 16);
        sacc[kb] =
            __builtin_amdgcn_mfma_f32_16x16x32_f16(kf, qf[ks], sacc[kb], 0, 0, 0);
      }
    }

    // mask (pre-scale -1e5 semantics => -12500 post-scale) + lane-local softmax
    const bool diag = (kt == qblk);
    float s[4][4];
    float pmax = -1e30f;
#pragma unroll
    for (int kb = 0; kb < 4; ++kb)
#pragma unroll
      for (int r = 0; r < 4; ++r) {
        float v = sacc[kb][r] * 0.125f;
        if (diag) {
          int kk = k0 + kb * 16 + g * 4 + r;
          if (kk > qrow) v = -12500.f;
        }
        s[kb][r] = v;
        pmax = fmaxf(pmax, v);
      }
    pmax = fmaxf(pmax, __shfl_xor(pmax, 16));
    pmax = fmaxf(pmax, __shfl_xor(pmax, 32));
    float mnew = fmaxf(m_run, pmax);
    float scale = __expf(m_run - mnew);
    float lsum = 0.f;
    ushort4 pk[4];
#pragma unroll
    for (int kb = 0; kb < 4; ++kb) {
      unsigned short* pp = (unsigned short*)&pk[kb];
#pragma unroll
      for (int r = 0; r < 4; ++r) {
        float p = __expf(s[kb][r] - mnew);
        lsum += p;
        pp[r] = f2h(p);
      }
    }
    lsum += __shfl_xor(lsum, 16);
    lsum += __shfl_xor(lsum, 32);
    l_run = l_run * scale + lsum;
    m_run = mnew;
#pragma unroll
    for (int hb = 0; hb < 4; ++hb) oacc[hb] *= scale;

    // P[q][key] into per-wave LDS tile (rows 144B)
#pragma unroll
    for (int kb = 0; kb < 4; ++kb)
      *(ushort4*)((char*)pw + q * 144 + kb * 32 + g * 8) = pk[kb];
    __syncthreads();  // conservative: make P visible/ordered before reads

    // O^T += V^T · P^T
#pragma unroll
    for (int ks = 0; ks < 2; ++ks) {
      half8 pf = *(const half8*)((const char*)pw + q * 144 + (g + 4 * ks) * 16);
#pragma unroll
      for (int hb = 0; hb < 4; ++hb) {
        int row = hb * 16 + q;  // hd row
        int cs = (g + 4 * ks) ^ (row & 7);
        half8 vf = *(const half8*)((const char*)Vt + row * 128 + cs * 16);
        oacc[hb] = __builtin_amdgcn_mfma_f32_16x16x32_f16(vf, pf, oacc[hb], 0, 0, 0);
      }
    }
  }

  // epilogue: O^T[hd][q] -> ctx[b*S+qrow][h*64+hd], normalize by l_run
  float inv = 1.f / l_run;
  unsigned short* cp = ctx + (size_t)(b * SS + qrow) * DD + h * HD;
#pragma unroll
  for (int hb = 0; hb < 4; ++hb) {
    ushort4 pk;
    unsigned short* pp = (unsigned short*)&pk;
#pragma unroll
    for (int r = 0; r < 4; ++r) pp[r] = f2h(oacc[hb][r] * inv);
    *(ushort4*)(cp + hb * 16 + g * 4) = pk;
  }
}

// ---------------------------------------------------------------------------
extern "C" void kernel_launch(void* const* d_in, const int* in_sizes, int n_in,
                              void* d_out, int out_size, void* d_ws,
                              size_t ws_size, hipStream_t stream) {
  const float* x = (const float*)d_in[0];       // [B,S,D]
  const float* w_attn = (const float*)d_in[1];  // [D,3D]
  const float* b_attn = (const float*)d_in[2];  // [3D]
  const float* w_proj = (const float*)d_in[3];  // [D,D]
  const float* b_proj = (const float*)d_in[4];  // [D]
  float* out = (float*)d_out;                   // [B,S,D] f32

  unsigned short* xB = (unsigned short*)d_ws;            // [M][D]
  unsigned short* qkvB = xB + (size_t)MM * DD;           // [M][3D] (Q,K used)
  unsigned short* vTb = qkvB + (size_t)MM * NQKV;        // [B*H*HD][S]
  unsigned short* ctxB = vTb + (size_t)BB * HH * HD * SS;  // [M][D]
  unsigned short* wqkvT = ctxB + (size_t)MM * DD;        // [3D][D]
  unsigned short* wprojT = wqkvT + (size_t)NQKV * DD;    // [D][D]

  cvt_f16<<<dim3(MM * DD / 4 / 256), 256, 0, stream>>>(x, xB, MM * DD / 4);
  transpose_f16<<<dim3(NQKV / 64, DD / 64), 256, 0, stream>>>(w_attn, wqkvT, DD, NQKV);
  transpose_f16<<<dim3(DD / 64, DD / 64), 256, 0, stream>>>(w_proj, wprojT, DD, DD);

  gemm_f16<0><<<dim3(NQKV / 128, MM / 128), 256, 0, stream>>>(
      xB, wqkvT, b_attn, qkvB, vTb, nullptr, MM, NQKV, DD);

  flash16<<<dim3(SS / 64, BB * HH), 256, 0, stream>>>(qkvB, vTb, ctxB);

  gemm_f16<1><<<dim3(DD / 128, MM / 128), 256, 0, stream>>>(
      ctxB, wprojT, b_proj, nullptr, nullptr, out, MM, DD, DD);
}

// Round 3
// 295.299 us; speedup vs baseline: 6.3880x; 1.1755x over previous
//
#include <hip/hip_runtime.h>
#include <hip/hip_bf16.h>

// Problem constants: B=4, S=2048, D=1024, H=16, HD=64
#define BB 4
#define SS 2048
#define DD 1024
#define HH 16
#define HD 64
#define MM (BB * SS)     // 8192
#define NQKV (3 * DD)    // 3072

typedef __attribute__((ext_vector_type(8))) _Float16 half8;
typedef __attribute__((ext_vector_type(4))) float f32x4;

static __device__ __forceinline__ unsigned short f2h(float f) {
  _Float16 h = (_Float16)f;
  return __builtin_bit_cast(unsigned short, h);
}

// async global->LDS, 16B per lane; LDS dest is wave-uniform base (+lane*16 by HW)
static __device__ __forceinline__ void gload_lds16(const void* g, void* l) {
  __builtin_amdgcn_global_load_lds(
      (const __attribute__((address_space(1))) unsigned int*)g,
      (__attribute__((address_space(3))) unsigned int*)l, 16, 0, 0);
}

// ---------------------------------------------------------------------------
// fp32 -> fp16 convert (flat, vectorized)
// ---------------------------------------------------------------------------
__global__ __launch_bounds__(256) void cvt_f16(const float* __restrict__ in,
                                               unsigned short* __restrict__ out,
                                               int n4) {
  int i = blockIdx.x * 256 + threadIdx.x;
  if (i < n4) {
    float4 v = ((const float4*)in)[i];
    ushort4 o;
    o.x = f2h(v.x); o.y = f2h(v.y); o.z = f2h(v.z); o.w = f2h(v.w);
    ((ushort4*)out)[i] = o;
  }
}

// ---------------------------------------------------------------------------
// transpose+convert: in [K][N] f32 -> out [N][K] f16, 64x64 tiles
// ---------------------------------------------------------------------------
__global__ __launch_bounds__(256) void transpose_f16(
    const float* __restrict__ in, unsigned short* __restrict__ out, int K, int N) {
  __shared__ float tile[64][65];
  const int k0 = blockIdx.y * 64, n0 = blockIdx.x * 64;
  const int t = threadIdx.x;
#pragma unroll
  for (int i = 0; i < 16; ++i) {
    int idx = i * 256 + t;
    int r = idx >> 6, c = idx & 63;
    tile[r][c] = in[(size_t)(k0 + r) * N + n0 + c];
  }
  __syncthreads();
#pragma unroll
  for (int i = 0; i < 16; ++i) {
    int idx = i * 256 + t;
    int r = idx >> 6, c = idx & 63;
    out[(size_t)(n0 + r) * K + k0 + c] = f2h(tile[c][r]);
  }
}

// ---------------------------------------------------------------------------
// fp16 MFMA GEMM: C[M,N] = A[M,K]f16 @ BT[N,K]f16^T + bias
// 128x128 tile, BK=32, 4 waves (2x2), each wave 64x64 via 4x4 16x16x32 MFMAs.
// 1-D grid with XCD-chunked swizzle (8 XCDs, nwg % 8 == 0).
// MODE 0: out f16 -> qkv buffer (cols<2048) + transposed V buffer (cols>=2048)
// MODE 1: out f32 -> Cf
// ---------------------------------------------------------------------------
template <int MODE>
__global__ __launch_bounds__(256) void gemm_f16(
    const unsigned short* __restrict__ A, const unsigned short* __restrict__ BT,
    const float* __restrict__ bias, unsigned short* __restrict__ Cq,
    unsigned short* __restrict__ vT, float* __restrict__ Cf, int M, int N, int K,
    int nx) {
  __shared__ __align__(16) unsigned short As[128 * 32];
  __shared__ __align__(16) unsigned short Bs[128 * 32];

  const int t = threadIdx.x;
  const int lane = t & 63;
  const int w = t >> 6;
  const int wr = w >> 1, wc = w & 1;

  const int nwg = gridDim.x;
  const int per = nwg >> 3;
  const int logical = (blockIdx.x & 7) * per + (blockIdx.x >> 3);
  const int bm = (logical / nx) * 128, bn = (logical % nx) * 128;

  f32x4 acc[4][4] = {};

  const int srow = (lane >> 2);
  const int sslot = (lane & 3);

  for (int k0 = 0; k0 < K; k0 += 32) {
    __syncthreads();
#pragma unroll
    for (int i = 0; i < 2; ++i) {
      int chunk = w * 2 + i;
      int row = chunk * 16 + srow;
      int cs = sslot ^ ((row >> 1) & 3);
      gload_lds16(A + (size_t)(bm + row) * K + k0 + cs * 8,
                  (char*)As + chunk * 1024);
      gload_lds16(BT + (size_t)(bn + row) * K + k0 + cs * 8,
                  (char*)Bs + chunk * 1024);
    }
    __syncthreads();

    half8 af[4], bf[4];
#pragma unroll
    for (int mb = 0; mb < 4; ++mb) {
      int row = wr * 64 + mb * 16 + (lane & 15);
      int cs = (lane >> 4) ^ ((row >> 1) & 3);
      af[mb] = *(const half8*)((const char*)As + row * 64 + cs * 16);
    }
#pragma unroll
    for (int nb = 0; nb < 4; ++nb) {
      int row = wc * 64 + nb * 16 + (lane & 15);
      int cs = (lane >> 4) ^ ((row >> 1) & 3);
      bf[nb] = *(const half8*)((const char*)Bs + row * 64 + cs * 16);
    }
    __builtin_amdgcn_s_setprio(1);
#pragma unroll
    for (int mb = 0; mb < 4; ++mb)
#pragma unroll
      for (int nb = 0; nb < 4; ++nb)
        acc[mb][nb] = __builtin_amdgcn_mfma_f32_16x16x32_f16(
            af[mb], bf[nb], acc[mb][nb], 0, 0, 0);
    __builtin_amdgcn_s_setprio(0);
  }

  // epilogue. C/D frag: col = lane&15, row = (lane>>4)*4 + reg
  const int g = lane >> 4;
#pragma unroll
  for (int mb = 0; mb < 4; ++mb) {
#pragma unroll
    for (int nb = 0; nb < 4; ++nb) {
      int m0 = bm + wr * 64 + mb * 16 + g * 4;
      int n = bn + wc * 64 + nb * 16 + (lane & 15);
      float bv = bias[n];
      if (MODE == 0) {
        if (n < 2 * DD) {
#pragma unroll
          for (int r = 0; r < 4; ++r)
            Cq[(size_t)(m0 + r) * NQKV + n] = f2h(acc[mb][nb][r] + bv);
        } else {
          int h = (n - 2 * DD) >> 6;
          int hd = n & 63;
          int b = m0 >> 11, s0 = m0 & 2047;
          ushort4 pk;
          unsigned short* pp = (unsigned short*)&pk;
#pragma unroll
          for (int r = 0; r < 4; ++r) pp[r] = f2h(acc[mb][nb][r] + bv);
          *(ushort4*)&vT[((size_t)((b * HH + h) * HD + hd)) * SS + s0] = pk;
        }
      } else {
#pragma unroll
        for (int r = 0; r < 4; ++r)
          Cf[(size_t)(m0 + r) * N + n] = acc[mb][nb][r] + bv;
      }
    }
  }
}

// ---------------------------------------------------------------------------
// fp16 MFMA causal flash attention, work-balanced pairing.
// 1024 WGs (1D, XCD-chunked): WG handles q-blocks (p, 31-p) of one (b,h)
// -> constant 33 MFMA-tiles/WG; lo's K/V tiles are a subset of hi's.
// 256 thr = 4 waves; wave w owns rows w*16..+15 of both q-blocks.
// K/V double-buffered (1 barrier/tile); P is wave-local (no barrier),
// XOR-swizzled 128B rows. LDS = 40KB -> 4 WG/CU; VGPR capped 128.
// ---------------------------------------------------------------------------
__global__ __launch_bounds__(256, 4) void flash16(
    const unsigned short* __restrict__ qkv,  // [M][3072] f16 (Q,K cols valid)
    const unsigned short* __restrict__ vT,   // [B*H*HD][S] f16
    unsigned short* __restrict__ ctx) {      // [M][1024] f16
  __shared__ __align__(16) unsigned short Kt[2][64 * 64];
  __shared__ __align__(16) unsigned short Vt[2][64 * 64];
  __shared__ __align__(16) unsigned short Ps[4][16 * 64];  // per-wave P, swz

  const int tid = threadIdx.x, lane = tid & 63, w = tid >> 6;
  const int phys = blockIdx.x;
  const int logical = (phys & 7) * 128 + (phys >> 3);  // XCD-chunked
  const int bh = logical >> 4;
  const int p = logical & 15;
  const int b = bh >> 4, h = bh & 15;
  const int qHiB = 31 - p;

  const int q = lane & 15, g = lane >> 4;
  const int qrowLo = p * 64 + w * 16 + q;
  const int qrowHi = qHiB * 64 + w * 16 + q;

  const unsigned short* kg = qkv + (size_t)b * SS * NQKV + DD + h * HD;
  const unsigned short* vg = vT + (size_t)(b * HH + h) * HD * SS;

  half8 qfLo[2], qfHi[2];
  {
    const unsigned short* qp = qkv + (size_t)(b * SS + qrowLo) * NQKV + h * HD;
    qfLo[0] = *(const half8*)(qp + g * 8);
    qfLo[1] = *(const half8*)(qp + 32 + g * 8);
    const unsigned short* qp2 = qkv + (size_t)(b * SS + qrowHi) * NQKV + h * HD;
    qfHi[0] = *(const half8*)(qp2 + g * 8);
    qfHi[1] = *(const half8*)(qp2 + 32 + g * 8);
  }

  f32x4 oLo[4] = {}, oHi[4] = {};
  float mLo = -1e30f, lLo = 0.f, mHi = -1e30f, lHi = 0.f;

  unsigned short* pw = &Ps[w][0];
  const int srow = lane >> 3, sslot = lane & 7;

  auto STAGE = [&](int tt, int c) {
    const int k0s = tt * 64;
#pragma unroll
    for (int i = 0; i < 2; ++i) {
      int chunk = w * 2 + i;
      int row = chunk * 8 + srow;
      int cs = sslot ^ (row & 7);
      gload_lds16(kg + (size_t)(k0s + row) * NQKV + cs * 8,
                  (char*)Kt[c] + chunk * 1024);
      gload_lds16(vg + (size_t)row * SS + k0s + cs * 8,
                  (char*)Vt[c] + chunk * 1024);
    }
  };

  // one q-block's update against K/V tile in buffer `cur`
  auto QBLOCK = [&](const half8 (&qf)[2], f32x4 (&oa)[4], float& m_run,
                    float& l_run, int qrow, int k0, int cur, bool diag) {
    f32x4 sa[4] = {};
    __builtin_amdgcn_s_setprio(1);
#pragma unroll
    for (int ks = 0; ks < 2; ++ks)
#pragma unroll
      for (int kb = 0; kb < 4; ++kb) {
        int row = kb * 16 + q;
        int cs = (g + 4 * ks) ^ (row & 7);
        half8 kf = *(const half8*)((const char*)Kt[cur] + row * 128 + cs * 16);
        sa[kb] =
            __builtin_amdgcn_mfma_f32_16x16x32_f16(kf, qf[ks], sa[kb], 0, 0, 0);
      }
    __builtin_amdgcn_s_setprio(0);

    // scale + causal mask (pre-scale -1e5 => -12500 post-scale), row max
    float pmax = -1e30f;
#pragma unroll
    for (int kb = 0; kb < 4; ++kb)
#pragma unroll
      for (int r = 0; r < 4; ++r) {
        float v = sa[kb][r] * 0.125f;
        if (diag) {
          int kk = k0 + kb * 16 + g * 4 + r;
          if (kk > qrow) v = -12500.f;
        }
        sa[kb][r] = v;
        pmax = fmaxf(pmax, v);
      }
    pmax = fmaxf(pmax, __shfl_xor(pmax, 16));
    pmax = fmaxf(pmax, __shfl_xor(pmax, 32));
    // defer-max: only rescale when the running max grew by > 8
    if (!__all(pmax - m_run <= 8.0f)) {
      float mnew = fmaxf(m_run, pmax);
      float sc = __expf(m_run - mnew);
      l_run *= sc;
#pragma unroll
      for (int hb = 0; hb < 4; ++hb) oa[hb] *= sc;
      m_run = mnew;
    }
    float lsum = 0.f;
#pragma unroll
    for (int kb = 0; kb < 4; ++kb) {
      ushort4 pk;
      unsigned short* pp = (unsigned short*)&pk;
#pragma unroll
      for (int r = 0; r < 4; ++r) {
        float pv = __expf(sa[kb][r] - m_run);
        lsum += pv;
        pp[r] = f2h(pv);
      }
      int slot = (2 * kb + (g >> 1)) ^ (q & 7);
      *(ushort4*)((char*)pw + q * 128 + slot * 16 + (g & 1) * 8) = pk;
    }
    lsum += __shfl_xor(lsum, 16);
    lsum += __shfl_xor(lsum, 32);
    l_run += lsum;

    // O^T += V^T · P^T  (wave-local P: same-wave DS ordering, no barrier)
    __builtin_amdgcn_s_setprio(1);
#pragma unroll
    for (int ks = 0; ks < 2; ++ks) {
      int pslot = (g + 4 * ks) ^ (q & 7);
      half8 pf = *(const half8*)((const char*)pw + q * 128 + pslot * 16);
#pragma unroll
      for (int hb = 0; hb < 4; ++hb) {
        int row = hb * 16 + q;
        int cs = (g + 4 * ks) ^ (row & 7);
        half8 vf = *(const half8*)((const char*)Vt[cur] + row * 128 + cs * 16);
        oa[hb] =
            __builtin_amdgcn_mfma_f32_16x16x32_f16(vf, pf, oa[hb], 0, 0, 0);
      }
    }
    __builtin_amdgcn_s_setprio(0);
  };

  STAGE(0, 0);
  __syncthreads();

  const int nt = qHiB + 1;
  for (int t = 0; t < nt; ++t) {
    const int cur = t & 1;
    if (t + 1 < nt) STAGE(t + 1, cur ^ 1);  // async prefetch into other buffer
    const int k0 = t * 64;
    if (t <= p) QBLOCK(qfLo, oLo, mLo, lLo, qrowLo, k0, cur, t == p);
    QBLOCK(qfHi, oHi, mHi, lHi, qrowHi, k0, cur, t == qHiB);
    __syncthreads();  // compute(cur) done + prefetch(cur^1) drained
  }

  // epilogue: O^T[hd][q] -> ctx rows, normalize
  {
    float inv = 1.f / lLo;
    unsigned short* cp = ctx + (size_t)(b * SS + qrowLo) * DD + h * HD;
#pragma unroll
    for (int hb = 0; hb < 4; ++hb) {
      ushort4 pk;
      unsigned short* pp = (unsigned short*)&pk;
#pragma unroll
      for (int r = 0; r < 4; ++r) pp[r] = f2h(oLo[hb][r] * inv);
      *(ushort4*)(cp + hb * 16 + g * 4) = pk;
    }
  }
  {
    float inv = 1.f / lHi;
    unsigned short* cp = ctx + (size_t)(b * SS + qrowHi) * DD + h * HD;
#pragma unroll
    for (int hb = 0; hb < 4; ++hb) {
      ushort4 pk;
      unsigned short* pp = (unsigned short*)&pk;
#pragma unroll
      for (int r = 0; r < 4; ++r) pp[r] = f2h(oHi[hb][r] * inv);
      *(ushort4*)(cp + hb * 16 + g * 4) = pk;
    }
  }
}

// ---------------------------------------------------------------------------
extern "C" void kernel_launch(void* const* d_in, const int* in_sizes, int n_in,
                              void* d_out, int out_size, void* d_ws,
                              size_t ws_size, hipStream_t stream) {
  const float* x = (const float*)d_in[0];       // [B,S,D]
  const float* w_attn = (const float*)d_in[1];  // [D,3D]
  const float* b_attn = (const float*)d_in[2];  // [3D]
  const float* w_proj = (const float*)d_in[3];  // [D,D]
  const float* b_proj = (const float*)d_in[4];  // [D]
  float* out = (float*)d_out;                   // [B,S,D] f32

  unsigned short* xB = (unsigned short*)d_ws;              // [M][D]
  unsigned short* qkvB = xB + (size_t)MM * DD;             // [M][3D]
  unsigned short* vTb = qkvB + (size_t)MM * NQKV;          // [B*H*HD][S]
  unsigned short* ctxB = vTb + (size_t)BB * HH * HD * SS;  // [M][D]
  unsigned short* wqkvT = ctxB + (size_t)MM * DD;          // [3D][D]
  unsigned short* wprojT = wqkvT + (size_t)NQKV * DD;      // [D][D]

  cvt_f16<<<dim3(MM * DD / 4 / 256), 256, 0, stream>>>(x, xB, MM * DD / 4);
  transpose_f16<<<dim3(NQKV / 64, DD / 64), 256, 0, stream>>>(w_attn, wqkvT, DD,
                                                              NQKV);
  transpose_f16<<<dim3(DD / 64, DD / 64), 256, 0, stream>>>(w_proj, wprojT, DD,
                                                            DD);

  // 1) QKV = X @ W_attn + b_attn   (1536 WGs, %8==0)
  gemm_f16<0><<<dim3((NQKV / 128) * (MM / 128)), 256, 0, stream>>>(
      xB, wqkvT, b_attn, qkvB, vTb, nullptr, MM, NQKV, DD, NQKV / 128);

  // 2) paired causal flash attention (1024 WGs)
  flash16<<<dim3(1024), 256, 0, stream>>>(qkvB, vTb, ctxB);

  // 3) out = ctx @ W_proj + b_proj (512 WGs, %8==0)
  gemm_f16<1><<<dim3((DD / 128) * (MM / 128)), 256, 0, stream>>>(
      ctxB, wprojT, b_proj, nullptr, nullptr, out, MM, DD, DD, DD / 128);
}

// Round 4
// 288.707 us; speedup vs baseline: 6.5338x; 1.0228x over previous
//
#include <hip/hip_runtime.h>
#include <hip/hip_bf16.h>

// Problem constants: B=4, S=2048, D=1024, H=16, HD=64
#define BB 4
#define SS 2048
#define DD 1024
#define HH 16
#define HD 64
#define MM (BB * SS)     // 8192
#define NQKV (3 * DD)    // 3072

typedef __attribute__((ext_vector_type(8))) _Float16 half8;
typedef __attribute__((ext_vector_type(4))) float f32x4;

static __device__ __forceinline__ unsigned short f2h(float f) {
  _Float16 h = (_Float16)f;
  return __builtin_bit_cast(unsigned short, h);
}

// async global->LDS, 16B per lane; LDS dest is wave-uniform base (+lane*16 by HW)
static __device__ __forceinline__ void gload_lds16(const void* g, void* l) {
  __builtin_amdgcn_global_load_lds(
      (const __attribute__((address_space(1))) unsigned int*)g,
      (__attribute__((address_space(3))) unsigned int*)l, 16, 0, 0);
}

// ---------------------------------------------------------------------------
// fp32 -> fp16 convert (flat, vectorized)
// ---------------------------------------------------------------------------
__global__ __launch_bounds__(256) void cvt_f16(const float* __restrict__ in,
                                               unsigned short* __restrict__ out,
                                               int n4) {
  int i = blockIdx.x * 256 + threadIdx.x;
  if (i < n4) {
    float4 v = ((const float4*)in)[i];
    ushort4 o;
    o.x = f2h(v.x); o.y = f2h(v.y); o.z = f2h(v.z); o.w = f2h(v.w);
    ((ushort4*)out)[i] = o;
  }
}

// ---------------------------------------------------------------------------
// transpose+convert: in [K][N] f32 -> out [N][K] f16, 64x64 tiles
// ---------------------------------------------------------------------------
__global__ __launch_bounds__(256) void transpose_f16(
    const float* __restrict__ in, unsigned short* __restrict__ out, int K, int N) {
  __shared__ float tile[64][65];
  const int k0 = blockIdx.y * 64, n0 = blockIdx.x * 64;
  const int t = threadIdx.x;
#pragma unroll
  for (int i = 0; i < 16; ++i) {
    int idx = i * 256 + t;
    int r = idx >> 6, c = idx & 63;
    tile[r][c] = in[(size_t)(k0 + r) * N + n0 + c];
  }
  __syncthreads();
#pragma unroll
  for (int i = 0; i < 16; ++i) {
    int idx = i * 256 + t;
    int r = idx >> 6, c = idx & 63;
    out[(size_t)(n0 + r) * K + k0 + c] = f2h(tile[c][r]);
  }
}

// ---------------------------------------------------------------------------
// fp16 MFMA GEMM: C[M,N] = A[M,K]f16 @ BT[N,K]f16^T + bias
// 128x128 tile, BK=32, 4 waves (2x2), each wave 64x64 via 4x4 16x16x32 MFMAs.
// DOUBLE-BUFFERED 2-phase: STAGE(t+1) issued before compute(t), one barrier
// per K-step (T3-minimum). LDS 2x16KB. 1-D grid, XCD-chunked swizzle.
// MODE 0: out f16 -> qkv buffer (cols<2048) + transposed V buffer (cols>=2048)
// MODE 1: out f32 -> Cf
// ---------------------------------------------------------------------------
template <int MODE>
__global__ __launch_bounds__(256, 4) void gemm_f16(
    const unsigned short* __restrict__ A, const unsigned short* __restrict__ BT,
    const float* __restrict__ bias, unsigned short* __restrict__ Cq,
    unsigned short* __restrict__ vT, float* __restrict__ Cf, int M, int N, int K,
    int nx) {
  __shared__ __align__(16) unsigned short As[2][128 * 32];
  __shared__ __align__(16) unsigned short Bs[2][128 * 32];

  const int t = threadIdx.x;
  const int lane = t & 63;
  const int w = t >> 6;
  const int wr = w >> 1, wc = w & 1;

  const int nwg = gridDim.x;
  const int per = nwg >> 3;
  const int logical = (blockIdx.x & 7) * per + (blockIdx.x >> 3);
  const int bm = (logical / nx) * 128, bn = (logical % nx) * 128;

  f32x4 acc[4][4] = {};

  const int srow = (lane >> 2);
  const int sslot = (lane & 3);

  auto STAGE = [&](int k0, int c) {
#pragma unroll
    for (int i = 0; i < 2; ++i) {
      int chunk = w * 2 + i;
      int row = chunk * 16 + srow;
      int cs = sslot ^ ((row >> 1) & 3);
      gload_lds16(A + (size_t)(bm + row) * K + k0 + cs * 8,
                  (char*)As[c] + chunk * 1024);
      gload_lds16(BT + (size_t)(bn + row) * K + k0 + cs * 8,
                  (char*)Bs[c] + chunk * 1024);
    }
  };

  STAGE(0, 0);
  __syncthreads();

  const int nsteps = K >> 5;
  for (int ks = 0; ks < nsteps; ++ks) {
    const int cur = ks & 1;
    if (ks + 1 < nsteps) STAGE((ks + 1) * 32, cur ^ 1);  // async prefetch

    half8 af[4], bf[4];
#pragma unroll
    for (int mb = 0; mb < 4; ++mb) {
      int row = wr * 64 + mb * 16 + (lane & 15);
      int cs = (lane >> 4) ^ ((row >> 1) & 3);
      af[mb] = *(const half8*)((const char*)As[cur] + row * 64 + cs * 16);
    }
#pragma unroll
    for (int nb = 0; nb < 4; ++nb) {
      int row = wc * 64 + nb * 16 + (lane & 15);
      int cs = (lane >> 4) ^ ((row >> 1) & 3);
      bf[nb] = *(const half8*)((const char*)Bs[cur] + row * 64 + cs * 16);
    }
    __builtin_amdgcn_s_setprio(1);
#pragma unroll
    for (int mb = 0; mb < 4; ++mb)
#pragma unroll
      for (int nb = 0; nb < 4; ++nb)
        acc[mb][nb] = __builtin_amdgcn_mfma_f32_16x16x32_f16(
            af[mb], bf[nb], acc[mb][nb], 0, 0, 0);
    __builtin_amdgcn_s_setprio(0);
    __syncthreads();  // compute(cur) done by all waves + prefetch landed
  }

  // epilogue. C/D frag: col = lane&15, row = (lane>>4)*4 + reg
  const int g = lane >> 4;
#pragma unroll
  for (int mb = 0; mb < 4; ++mb) {
#pragma unroll
    for (int nb = 0; nb < 4; ++nb) {
      int m0 = bm + wr * 64 + mb * 16 + g * 4;
      int n = bn + wc * 64 + nb * 16 + (lane & 15);
      float bv = bias[n];
      if (MODE == 0) {
        if (n < 2 * DD) {
#pragma unroll
          for (int r = 0; r < 4; ++r)
            Cq[(size_t)(m0 + r) * NQKV + n] = f2h(acc[mb][nb][r] + bv);
        } else {
          int h = (n - 2 * DD) >> 6;
          int hd = n & 63;
          int b = m0 >> 11, s0 = m0 & 2047;
          ushort4 pk;
          unsigned short* pp = (unsigned short*)&pk;
#pragma unroll
          for (int r = 0; r < 4; ++r) pp[r] = f2h(acc[mb][nb][r] + bv);
          *(ushort4*)&vT[((size_t)((b * HH + h) * HD + hd)) * SS + s0] = pk;
        }
      } else {
#pragma unroll
        for (int r = 0; r < 4; ++r)
          Cf[(size_t)(m0 + r) * N + n] = acc[mb][nb][r] + bv;
      }
    }
  }
}

// ---------------------------------------------------------------------------
// fp16 MFMA causal flash attention, work-balanced pairing, base-2 softmax.
// 1024 WGs (1D, XCD-chunked): WG handles q-blocks (p, 31-p) of one (b,h).
// 256 thr = 4 waves; wave w owns rows w*16..+15 of both q-blocks.
// K/V double-buffered (1 barrier/tile); P is wave-local (no barrier).
// LDS = 40KB -> 4 WG/CU; VGPR capped 128.
// ---------------------------------------------------------------------------
#define C2F 0.180336880f   /* 0.125 * log2(e) */
#define MASK2 -18000.0f    /* -1e5 * 0.125 * log2(e) ~ -18034 */

__global__ __launch_bounds__(256, 4) void flash16(
    const unsigned short* __restrict__ qkv,  // [M][3072] f16 (Q,K cols valid)
    const unsigned short* __restrict__ vT,   // [B*H*HD][S] f16
    unsigned short* __restrict__ ctx) {      // [M][1024] f16
  __shared__ __align__(16) unsigned short Kt[2][64 * 64];
  __shared__ __align__(16) unsigned short Vt[2][64 * 64];
  __shared__ __align__(16) unsigned short Ps[4][16 * 64];  // per-wave P, swz

  const int tid = threadIdx.x, lane = tid & 63, w = tid >> 6;
  const int phys = blockIdx.x;
  const int logical = (phys & 7) * 128 + (phys >> 3);  // XCD-chunked
  const int bh = logical >> 4;
  const int p = logical & 15;
  const int b = bh >> 4, h = bh & 15;
  const int qHiB = 31 - p;

  const int q = lane & 15, g = lane >> 4;
  const int qrowLo = p * 64 + w * 16 + q;
  const int qrowHi = qHiB * 64 + w * 16 + q;

  const unsigned short* kg = qkv + (size_t)b * SS * NQKV + DD + h * HD;
  const unsigned short* vg = vT + (size_t)(b * HH + h) * HD * SS;

  half8 qfLo[2], qfHi[2];
  {
    const unsigned short* qp = qkv + (size_t)(b * SS + qrowLo) * NQKV + h * HD;
    qfLo[0] = *(const half8*)(qp + g * 8);
    qfLo[1] = *(const half8*)(qp + 32 + g * 8);
    const unsigned short* qp2 = qkv + (size_t)(b * SS + qrowHi) * NQKV + h * HD;
    qfHi[0] = *(const half8*)(qp2 + g * 8);
    qfHi[1] = *(const half8*)(qp2 + 32 + g * 8);
  }

  f32x4 oLo[4] = {}, oHi[4] = {};
  float mLo = -1e30f, lLo = 0.f, mHi = -1e30f, lHi = 0.f;

  unsigned short* pw = &Ps[w][0];
  const int srow = lane >> 3, sslot = lane & 7;

  auto STAGE = [&](int tt, int c) {
    const int k0s = tt * 64;
#pragma unroll
    for (int i = 0; i < 2; ++i) {
      int chunk = w * 2 + i;
      int row = chunk * 8 + srow;
      int cs = sslot ^ (row & 7);
      gload_lds16(kg + (size_t)(k0s + row) * NQKV + cs * 8,
                  (char*)Kt[c] + chunk * 1024);
      gload_lds16(vg + (size_t)row * SS + k0s + cs * 8,
                  (char*)Vt[c] + chunk * 1024);
    }
  };

  // one q-block's update against K/V tile in buffer `cur` (base-2 softmax)
  auto QBLOCK = [&](const half8 (&qf)[2], f32x4 (&oa)[4], float& m_run,
                    float& l_run, int qrow, int k0, int cur, bool diag) {
    f32x4 sa[4] = {};
    __builtin_amdgcn_s_setprio(1);
#pragma unroll
    for (int ks = 0; ks < 2; ++ks)
#pragma unroll
      for (int kb = 0; kb < 4; ++kb) {
        int row = kb * 16 + q;
        int cs = (g + 4 * ks) ^ (row & 7);
        half8 kf = *(const half8*)((const char*)Kt[cur] + row * 128 + cs * 16);
        sa[kb] =
            __builtin_amdgcn_mfma_f32_16x16x32_f16(kf, qf[ks], sa[kb], 0, 0, 0);
      }
    __builtin_amdgcn_s_setprio(0);

    // base-2 scale + causal mask, row max
    float pmax = -1e30f;
#pragma unroll
    for (int kb = 0; kb < 4; ++kb)
#pragma unroll
      for (int r = 0; r < 4; ++r) {
        float v = sa[kb][r] * C2F;
        if (diag) {
          int kk = k0 + kb * 16 + g * 4 + r;
          if (kk > qrow) v = MASK2;
        }
        sa[kb][r] = v;
        pmax = fmaxf(pmax, v);
      }
    pmax = fmaxf(pmax, __shfl_xor(pmax, 16));
    pmax = fmaxf(pmax, __shfl_xor(pmax, 32));
    // defer-max: only rescale when the running max grew by > 8/ln2
    if (!__all(pmax - m_run <= 11.5f)) {
      float mnew = fmaxf(m_run, pmax);
      float sc = __builtin_amdgcn_exp2f(m_run - mnew);
      l_run *= sc;
#pragma unroll
      for (int hb = 0; hb < 4; ++hb) oa[hb] *= sc;
      m_run = mnew;
    }
    float lsum = 0.f;
#pragma unroll
    for (int kb = 0; kb < 4; ++kb) {
      ushort4 pk;
      unsigned short* pp = (unsigned short*)&pk;
#pragma unroll
      for (int r = 0; r < 4; ++r) {
        float pv = __builtin_amdgcn_exp2f(sa[kb][r] - m_run);
        lsum += pv;
        pp[r] = f2h(pv);
      }
      int slot = (2 * kb + (g >> 1)) ^ (q & 7);
      *(ushort4*)((char*)pw + q * 128 + slot * 16 + (g & 1) * 8) = pk;
    }
    lsum += __shfl_xor(lsum, 16);
    lsum += __shfl_xor(lsum, 32);
    l_run += lsum;

    // O^T += V^T · P^T  (wave-local P: same-wave DS ordering, no barrier)
    __builtin_amdgcn_s_setprio(1);
#pragma unroll
    for (int ks = 0; ks < 2; ++ks) {
      int pslot = (g + 4 * ks) ^ (q & 7);
      half8 pf = *(const half8*)((const char*)pw + q * 128 + pslot * 16);
#pragma unroll
      for (int hb = 0; hb < 4; ++hb) {
        int row = hb * 16 + q;
        int cs = (g + 4 * ks) ^ (row & 7);
        half8 vf = *(const half8*)((const char*)Vt[cur] + row * 128 + cs * 16);
        oa[hb] =
            __builtin_amdgcn_mfma_f32_16x16x32_f16(vf, pf, oa[hb], 0, 0, 0);
      }
    }
    __builtin_amdgcn_s_setprio(0);
  };

  STAGE(0, 0);
  __syncthreads();

  const int nt = qHiB + 1;
  for (int t = 0; t < nt; ++t) {
    const int cur = t & 1;
    if (t + 1 < nt) STAGE(t + 1, cur ^ 1);  // async prefetch into other buffer
    const int k0 = t * 64;
    if (t <= p) QBLOCK(qfLo, oLo, mLo, lLo, qrowLo, k0, cur, t == p);
    QBLOCK(qfHi, oHi, mHi, lHi, qrowHi, k0, cur, t == qHiB);
    __syncthreads();  // compute(cur) done + prefetch(cur^1) drained
  }

  // epilogue: O^T[hd][q] -> ctx rows, normalize
  {
    float inv = 1.f / lLo;
    unsigned short* cp = ctx + (size_t)(b * SS + qrowLo) * DD + h * HD;
#pragma unroll
    for (int hb = 0; hb < 4; ++hb) {
      ushort4 pk;
      unsigned short* pp = (unsigned short*)&pk;
#pragma unroll
      for (int r = 0; r < 4; ++r) pp[r] = f2h(oLo[hb][r] * inv);
      *(ushort4*)(cp + hb * 16 + g * 4) = pk;
    }
  }
  {
    float inv = 1.f / lHi;
    unsigned short* cp = ctx + (size_t)(b * SS + qrowHi) * DD + h * HD;
#pragma unroll
    for (int hb = 0; hb < 4; ++hb) {
      ushort4 pk;
      unsigned short* pp = (unsigned short*)&pk;
#pragma unroll
      for (int r = 0; r < 4; ++r) pp[r] = f2h(oHi[hb][r] * inv);
      *(ushort4*)(cp + hb * 16 + g * 4) = pk;
    }
  }
}

// ---------------------------------------------------------------------------
extern "C" void kernel_launch(void* const* d_in, const int* in_sizes, int n_in,
                              void* d_out, int out_size, void* d_ws,
                              size_t ws_size, hipStream_t stream) {
  const float* x = (const float*)d_in[0];       // [B,S,D]
  const float* w_attn = (const float*)d_in[1];  // [D,3D]
  const float* b_attn = (const float*)d_in[2];  // [3D]
  const float* w_proj = (const float*)d_in[3];  // [D,D]
  const float* b_proj = (const float*)d_in[4];  // [D]
  float* out = (float*)d_out;                   // [B,S,D] f32

  unsigned short* xB = (unsigned short*)d_ws;              // [M][D]
  unsigned short* qkvB = xB + (size_t)MM * DD;             // [M][3D]
  unsigned short* vTb = qkvB + (size_t)MM * NQKV;          // [B*H*HD][S]
  unsigned short* ctxB = vTb + (size_t)BB * HH * HD * SS;  // [M][D]
  unsigned short* wqkvT = ctxB + (size_t)MM * DD;          // [3D][D]
  unsigned short* wprojT = wqkvT + (size_t)NQKV * DD;      // [D][D]

  cvt_f16<<<dim3(MM * DD / 4 / 256), 256, 0, stream>>>(x, xB, MM * DD / 4);
  transpose_f16<<<dim3(NQKV / 64, DD / 64), 256, 0, stream>>>(w_attn, wqkvT, DD,
                                                              NQKV);
  transpose_f16<<<dim3(DD / 64, DD / 64), 256, 0, stream>>>(w_proj, wprojT, DD,
                                                            DD);

  // 1) QKV = X @ W_attn + b_attn   (1536 WGs, %8==0)
  gemm_f16<0><<<dim3((NQKV / 128) * (MM / 128)), 256, 0, stream>>>(
      xB, wqkvT, b_attn, qkvB, vTb, nullptr, MM, NQKV, DD, NQKV / 128);

  // 2) paired causal flash attention (1024 WGs)
  flash16<<<dim3(1024), 256, 0, stream>>>(qkvB, vTb, ctxB);

  // 3) out = ctx @ W_proj + b_proj (512 WGs, %8==0)
  gemm_f16<1><<<dim3((DD / 128) * (MM / 128)), 256, 0, stream>>>(
      ctxB, wprojT, b_proj, nullptr, nullptr, out, MM, DD, DD, DD / 128);
}